// Round 11
// baseline (1996.329 us; speedup 1.0000x reference)
//
#include <hip/hip_runtime.h>
#include <hip/hip_bf16.h>
#include <math.h>

#define DD 768
#define HH 8
#define DHH 96
#define NL 3
#define NN 20000
#define EE 100000

typedef __attribute__((ext_vector_type(8))) __bf16 bf16x8;
typedef __attribute__((ext_vector_type(4))) float f32x4;
typedef __attribute__((ext_vector_type(8))) unsigned short u16x8;

__host__ __device__ static inline int imin(int a, int b) { return a < b ? a : b; }

__device__ inline float b2f(unsigned short u) {
    union { unsigned int v; float f; } x; x.v = ((unsigned int)u) << 16; return x.f;
}
__device__ inline unsigned short f2b_rne(float f) {
    union { float f; unsigned int v; } x; x.f = f;
    unsigned int v = x.v;
    return (unsigned short)((v + 0x7FFFu + ((v >> 16) & 1u)) >> 16);
}
__device__ inline void b2f2(unsigned int u, float& lo, float& hi) {
    union { unsigned int v; float f; } x;
    x.v = u << 16; lo = x.f;
    x.v = u & 0xffff0000u; hi = x.f;
}
__device__ inline unsigned int packbf(float a, float b) {
    return (unsigned int)f2b_rne(a) | ((unsigned int)f2b_rne(b) << 16);
}

// ================= CSR build =================
__global__ void deg_kernel(const int* __restrict__ dst, int* __restrict__ cnt)
{
    int i = blockIdx.x * 256 + threadIdx.x;
    if (i < EE) atomicAdd(&cnt[dst[i]], 1);
}

__global__ __launch_bounds__(256)
void scan_kernel(const int* __restrict__ deg, int* __restrict__ rowptr, int* __restrict__ cursor)
{
    __shared__ int part[256];
    int t = threadIdx.x;
    const int per = (NN + 255) / 256;
    int lo = t * per, hi = imin(NN, lo + per);
    int s = 0;
    for (int i = lo; i < hi; i++) s += deg[i];
    part[t] = s;
    __syncthreads();
    if (t == 0) {
        int acc = 0;
        for (int i = 0; i < 256; i++) { int v = part[i]; part[i] = acc; acc += v; }
        rowptr[NN] = acc;
    }
    __syncthreads();
    int run = part[t];
    for (int i = lo; i < hi; i++) {
        rowptr[i] = run; cursor[i] = run;
        run += deg[i];
    }
}

__global__ void fill_perm(const int* __restrict__ src, const int* __restrict__ dst,
                          int* __restrict__ cursor, int* __restrict__ perm,
                          int* __restrict__ src_s)
{
    int e = blockIdx.x * 256 + threadIdx.x;
    if (e >= EE) return;
    int d = dst[e];
    int pos = atomicAdd(&cursor[d], 1);
    perm[pos] = e;
    src_s[pos] = src[e];
}

__global__ void degf_kernel(const int* __restrict__ rowptr, float* __restrict__ degf)
{
    int n = blockIdx.x * 256 + threadIdx.x;
    if (n < NN) degf[n] = (float)(rowptr[n + 1] - rowptr[n]);
}

// ================= conversions =================
__global__ void f2b_kernel(const float* __restrict__ in, unsigned short* __restrict__ out, int n8)
{
    int i = blockIdx.x * 256 + threadIdx.x;
    if (i >= n8) return;
    const float4* p = reinterpret_cast<const float4*>(in + (size_t)i * 8);
    float4 a = p[0], b = p[1];
    u16x8 o;
    o[0] = f2b_rne(a.x); o[1] = f2b_rne(a.y); o[2] = f2b_rne(a.z); o[3] = f2b_rne(a.w);
    o[4] = f2b_rne(b.x); o[5] = f2b_rne(b.y); o[6] = f2b_rne(b.z); o[7] = f2b_rne(b.w);
    *reinterpret_cast<u16x8*>(out + (size_t)i * 8) = o;
}

__global__ void f2b_gather(const float* __restrict__ in, const int* __restrict__ perm,
                           unsigned short* __restrict__ out)
{
    int i = blockIdx.x * 256 + threadIdx.x;
    if (i >= EE * 96) return;
    int m = i / 96;
    int d8 = (i % 96) * 8;
    int row = perm[m];
    const float4* p = reinterpret_cast<const float4*>(in + (size_t)row * DD + d8);
    float4 a = p[0], b = p[1];
    u16x8 o;
    o[0] = f2b_rne(a.x); o[1] = f2b_rne(a.y); o[2] = f2b_rne(a.z); o[3] = f2b_rne(a.w);
    o[4] = f2b_rne(b.x); o[5] = f2b_rne(b.y); o[6] = f2b_rne(b.z); o[7] = f2b_rne(b.w);
    *reinterpret_cast<u16x8*>(out + (size_t)m * DD + d8) = o;
}

// ---- W [Kin][768] fp32 -> Wt[n*out_ld + out_off + k] bf16 ; z-batched ----
__global__ void transpose_w(const float* __restrict__ W, unsigned short* __restrict__ Wt,
                            int Kin, int out_ld, int out_off,
                            size_t strideW, size_t strideWt)
{
    __shared__ float tile[32][33];
    int z = blockIdx.z;
    W  += (size_t)z * strideW;
    Wt += (size_t)z * strideWt;
    int kb = blockIdx.x * 32, nb = blockIdx.y * 32;
    int tx = threadIdx.x & 31, ty = threadIdx.x >> 5;
#pragma unroll
    for (int i = 0; i < 32; i += 8)
        tile[ty + i][tx] = W[(size_t)(kb + ty + i) * DD + nb + tx];
    __syncthreads();
#pragma unroll
    for (int i = 0; i < 32; i += 8)
        Wt[(size_t)(nb + ty + i) * out_ld + out_off + kb + tx] = f2b_rne(tile[tx][ty + i]);
}

// bf[l][n] = bla1[l][n] + sum_k blx[l][k] * Wla1_top[l][k][n]   (grid: (3, NL))
__global__ void biasf_kernel(const float* __restrict__ blx, const float* __restrict__ Wla1,
                             const float* __restrict__ bla1, float* __restrict__ bf)
{
    int l = blockIdx.y;
    const float* blxl  = blx  + (size_t)l * DD;
    const float* Wla1l = Wla1 + (size_t)l * 2 * DD * DD;
    const float* bla1l = bla1 + (size_t)l * DD;
    float* bfl = bf + (size_t)l * DD;
    int n = blockIdx.x * 256 + threadIdx.x;
    if (n >= DD) return;
    float s = bla1l[n];
    for (int k = 0; k < DD; k++) s += blxl[k] * Wla1l[(size_t)k * DD + n];
    bfl[n] = s;
}

// grid (9, NL)
__global__ void biasqkv_kernel(const float* __restrict__ bq, const float* __restrict__ bv,
                               float* __restrict__ bqkv)
{
    int l = blockIdx.y;
    int i = blockIdx.x * 256 + threadIdx.x;
    if (i >= 3 * DD) return;
    float v = 0.f;
    if (i < DD) v = bq[(size_t)l * DD + i];
    else if (i >= 2 * DD) v = bv[(size_t)l * DD + i - 2 * DD];
    bqkv[(size_t)l * 3 * DD + i] = v;
}

// ================= MFMA GEMM =================
// C[M,Nw] = concat(A0,A1)[M,K] @ W + bias*rowscale ; Wt [Nw][K] bf16 n-major.
// 256x128 tile, 8 waves, BK=64. Double-buffered LDS 2-phase pipeline:
//   STAGE(next buf) issued BEFORE ds_read+MFMA(current buf); one vmcnt(0)+barrier per step.
// XCD-chunked bijective swizzle; z-batched; bf16 C via one 256x136 padded LDS staging.
__global__ __launch_bounds__(512, 2)
void gemm_mfma(const unsigned short* __restrict__ A0,
               const unsigned short* __restrict__ A1,
               const unsigned short* __restrict__ Wt,
               const float* __restrict__ bias,
               const float* __restrict__ rowscale,
               float* __restrict__ C32,
               unsigned short* __restrict__ C16,
               int M, int K, int Nw,
               size_t bsA, size_t bsW, size_t bsC)
{
    __shared__ __align__(16) char smem[98304];   // 2 x (As 32KB + Bs 16KB)
    const int z = blockIdx.z;
    A0 += (size_t)z * bsA;
    Wt += (size_t)z * bsW;
    if (C32) C32 += (size_t)z * bsC;
    if (C16) C16 += (size_t)z * bsC;
    const int t = threadIdx.x;
    const int l = t & 63;
    const int w = t >> 6;            // wave 0..7
    const int wm = w & 3, wn = w >> 2;

    // ---- XCD-chunked bijective swizzle (m204) ----
    const int gx = gridDim.x;
    const int nwg = gx * gridDim.y;
    const int lin = blockIdx.y * gx + blockIdx.x;
    const int xcd = lin & 7, pos = lin >> 3;
    const int q8 = nwg >> 3, r8 = nwg & 7;
    const int base = (xcd < r8) ? xcd * (q8 + 1) : r8 * (q8 + 1) + (xcd - r8) * q8;
    const int swz = base + pos;
    const int bn = swz % gx, bm = swz / gx;

    const int srow = t >> 3;                      // 0..63
    const int ssrc = ((t & 7) ^ (srow & 7)) * 8;  // swizzled source col (bf16)

    const int lane_r = l & 15;
    const int lane_k = l >> 4;

    // stage one K-step (BK=64) into buffer `buf`
    auto STAGE = [&](int buf, int k0) {
        char* As = smem + buf * 49152;
        char* Bs = As + 32768;
        const unsigned short* Ap; int kbase;
        if (k0 < DD) { Ap = A0; kbase = k0; }
        else         { Ap = A1; kbase = k0 - DD; }
#pragma unroll
        for (int i = 0; i < 4; i++) {
            int grow = bm * 256 + i * 64 + srow;
            char* ldstA = As + ((i * 64 + w * 8) << 7);
            if (grow < M) {
                const unsigned short* g = Ap + (size_t)grow * DD + kbase + ssrc;
                __builtin_amdgcn_global_load_lds(
                    (const __attribute__((address_space(1))) void*)g,
                    (__attribute__((address_space(3))) void*)ldstA, 16, 0, 0);
            }
        }
#pragma unroll
        for (int i = 0; i < 2; i++) {
            int gn = bn * 128 + i * 64 + srow;
            const unsigned short* gB = Wt + (size_t)gn * K + k0 + ssrc;
            char* ldstB = Bs + ((i * 64 + w * 8) << 7);
            __builtin_amdgcn_global_load_lds(
                (const __attribute__((address_space(1))) void*)gB,
                (__attribute__((address_space(3))) void*)ldstB, 16, 0, 0);
        }
    };

    f32x4 acc[4][4];
#pragma unroll
    for (int m = 0; m < 4; m++)
#pragma unroll
        for (int n = 0; n < 4; n++) acc[m][n] = (f32x4){0.f, 0.f, 0.f, 0.f};

    const int nt = K >> 6;
    STAGE(0, 0);
    __syncthreads();                 // prologue drain (vmcnt0 + barrier)
    int cur = 0;
    for (int tt = 0; tt < nt; tt++) {
        if (tt + 1 < nt) STAGE(cur ^ 1, (tt + 1) << 6);   // next-tile loads in flight
        char* As = smem + cur * 49152;
        char* Bs = As + 32768;
        __builtin_amdgcn_s_setprio(1);
#pragma unroll
        for (int kk = 0; kk < 2; kk++) {
            bf16x8 af[4], bfr[4];
#pragma unroll
            for (int m = 0; m < 4; m++) {
                int r = wm * 64 + m * 16 + lane_r;
                int slot = (kk * 4 + lane_k) ^ (r & 7);
                af[m] = *reinterpret_cast<const bf16x8*>(As + r * 128 + slot * 16);
            }
#pragma unroll
            for (int n = 0; n < 4; n++) {
                int r = wn * 64 + n * 16 + lane_r;
                int slot = (kk * 4 + lane_k) ^ (r & 7);
                bfr[n] = *reinterpret_cast<const bf16x8*>(Bs + r * 128 + slot * 16);
            }
#pragma unroll
            for (int m = 0; m < 4; m++)
#pragma unroll
                for (int n = 0; n < 4; n++)
                    acc[m][n] = __builtin_amdgcn_mfma_f32_16x16x32_bf16(
                        af[m], bfr[n], acc[m][n], 0, 0, 0);
        }
        __builtin_amdgcn_s_setprio(0);
        __syncthreads();             // drains next-tile vmcnt + syncs buffer reuse
        cur ^= 1;
    }

    // ---- fp32 direct path ----
    if (C32) {
#pragma unroll
        for (int n = 0; n < 4; n++) {
            int col = bn * 128 + wn * 64 + n * 16 + lane_r;
            float badd = bias ? bias[col] : 0.f;
#pragma unroll
            for (int m = 0; m < 4; m++) {
#pragma unroll
                for (int j = 0; j < 4; j++) {
                    int r = bm * 256 + wm * 64 + m * 16 + lane_k * 4 + j;
                    if (r < M) {
                        float bs = rowscale ? rowscale[r] : 1.f;
                        C32[(size_t)r * Nw + col] = acc[m][n][j] + badd * bs;
                    }
                }
            }
        }
    }
    // ---- bf16 path: one 256x136 padded staging tile (69.6KB of the 96KB) ----
    if (C16) {
        unsigned short* cs = (unsigned short*)smem;
#pragma unroll
        for (int n = 0; n < 4; n++) {
            int lcol = wn * 64 + n * 16 + lane_r;
            float badd = bias ? bias[bn * 128 + lcol] : 0.f;
#pragma unroll
            for (int m = 0; m < 4; m++) {
#pragma unroll
                for (int j = 0; j < 4; j++) {
                    int lr = wm * 64 + m * 16 + lane_k * 4 + j;     // 0..255
                    int r = bm * 256 + lr;
                    float bs = rowscale ? (r < M ? rowscale[r] : 0.f) : 1.f;
                    cs[lr * 136 + lcol] = f2b_rne(acc[m][n][j] + badd * bs);
                }
            }
        }
        __syncthreads();
        // 512 threads over 256 rows x 128 cols: 2 threads/row, 64 cols = 8 u16x8 each
        int rr = t >> 1, half = t & 1;
        int grow = bm * 256 + rr;
        if (grow < M) {
            u16x8* dst = reinterpret_cast<u16x8*>(C16 + (size_t)grow * Nw + bn * 128 + half * 64);
            const u16x8* s = reinterpret_cast<const u16x8*>(cs + rr * 136 + half * 64);
#pragma unroll
            for (int c = 0; c < 8; c++) dst[c] = s[c];
        }
    }
}

// ================= fused edge attention + aggregation =================
__global__ __launch_bounds__(128)
void edge_fused(const unsigned short* __restrict__ kea,
                const unsigned short* __restrict__ qkv,
                const float* __restrict__ Waw, const float* __restrict__ baw,
                const int* __restrict__ rowptr, const int* __restrict__ src_s,
                unsigned short* __restrict__ agg)
{
    __shared__ float awsh[HH];
    __shared__ float WawS[HH * HH];
    __shared__ float bawS[HH];
    const int n = blockIdx.x;
    const int t = threadIdx.x;      // 0..127, 6 features each
    const int d0 = t * 6;
    const int h = t >> 4;           // 16 threads per head
    if (t < HH * HH) WawS[t] = Waw[t];
    if (t < HH) bawS[t] = baw[t];
    const int jlo = rowptr[n], jhi = rowptr[n + 1];
    const unsigned int* qr = reinterpret_cast<const unsigned int*>(qkv + (size_t)n * (3 * DD) + d0);
    float q[6];
    b2f2(qr[0], q[0], q[1]); b2f2(qr[1], q[2], q[3]); b2f2(qr[2], q[4], q[5]);
    float acc[6] = {0.f, 0.f, 0.f, 0.f, 0.f, 0.f};
    float sa = 0.f;
    constexpr float rs = 0.03608439182435161f; // 1/sqrt(768)
    __syncthreads();
    for (int j = jlo; j < jhi; j++) {
        int s = src_s[j];
        const unsigned int* ke = reinterpret_cast<const unsigned int*>(kea + (size_t)j * DD + d0);
        const unsigned int* kr = reinterpret_cast<const unsigned int*>(qkv + (size_t)s * (3 * DD) + DD + d0);
        const unsigned int* vr = reinterpret_cast<const unsigned int*>(qkv + (size_t)s * (3 * DD) + 2 * DD + d0);
        float part = 0.f;
        float ka, kb2, va, vb;
#pragma unroll
        for (int c = 0; c < 3; c++) {
            b2f2(ke[c], ka, kb2);
            b2f2(kr[c], va, vb);
            part = fmaf(q[2 * c], ka + va, part);
            part = fmaf(q[2 * c + 1], kb2 + vb, part);
        }
        part += __shfl_xor(part, 1);
        part += __shfl_xor(part, 2);
        part += __shfl_xor(part, 4);
        part += __shfl_xor(part, 8);
        if ((t & 15) == 0) awsh[h] = part;
        __syncthreads();
        float zz = bawS[h];
#pragma unroll
        for (int h2 = 0; h2 < HH; h2++) {
            float aw = awsh[h2] * rs;
            float tt = aw > 0.f ? aw : 0.2f * aw;
            zz = fmaf(tt, WawS[h2 * HH + h], zz);
        }
        float a = expf(zz);
        sa += a;
        float v0, v1;
#pragma unroll
        for (int c = 0; c < 3; c++) {
            b2f2(vr[c], v0, v1);
            acc[2 * c]     = fmaf(a, v0, acc[2 * c]);
            acc[2 * c + 1] = fmaf(a, v1, acc[2 * c + 1]);
        }
        __syncthreads();
    }
    float inv = (sa == 0.f) ? 1.f : 1.f / sa;
    unsigned int* ag = reinterpret_cast<unsigned int*>(agg + (size_t)n * DD + d0);
    ag[0] = packbf(acc[0] * inv, acc[1] * inv);
    ag[1] = packbf(acc[2] * inv, acc[3] * inv);
    ag[2] = packbf(acc[4] * inv, acc[5] * inv);
}

// one wave per node: z = lrelu(g)@Wla2 + bla2 ; la = softmax(z) ; out = x*la0 + h*la1
__global__ __launch_bounds__(256)
void combine_kernel(const unsigned short* __restrict__ g, const float* __restrict__ Wla2,
                    const float* __restrict__ bla2, unsigned short* __restrict__ x16,
                    const unsigned short* __restrict__ h, float* __restrict__ outf, int Nn)
{
    int w = threadIdx.x >> 6;
    int lane = threadIdx.x & 63;
    int n = blockIdx.x * 4 + w;
    if (n >= Nn) return;
    float z0 = 0.f, z1 = 0.f;
#pragma unroll
    for (int p = 0; p < 3; p++) {
        int d = p * 256 + lane * 4;
        const unsigned short* gp = g + (size_t)n * DD + d;
#pragma unroll
        for (int j = 0; j < 4; j++) {
            float gv = b2f(gp[j]);
            float tt = gv > 0.f ? gv : 0.2f * gv;
            z0 = fmaf(tt, Wla2[(d + j) * 2 + 0], z0);
            z1 = fmaf(tt, Wla2[(d + j) * 2 + 1], z1);
        }
    }
#pragma unroll
    for (int off = 32; off > 0; off >>= 1) {
        z0 += __shfl_xor(z0, off);
        z1 += __shfl_xor(z1, off);
    }
    z0 += bla2[0]; z1 += bla2[1];
    float mx = fmaxf(z0, z1);
    float e0v = expf(z0 - mx), e1v = expf(z1 - mx);
    float inv = 1.f / (e0v + e1v);
    float la0 = e0v * inv, la1 = e1v * inv;
#pragma unroll
    for (int p = 0; p < 3; p++) {
        int d = p * 256 + lane * 4;
        unsigned short* xp = x16 + (size_t)n * DD + d;
        const unsigned short* hp = h + (size_t)n * DD + d;
        float o[4];
#pragma unroll
        for (int j = 0; j < 4; j++)
            o[j] = b2f(xp[j]) * la0 + b2f(hp[j]) * la1;
#pragma unroll
        for (int j = 0; j < 4; j++) xp[j] = f2b_rne(o[j]);
        if (outf) {
            float4 ov = make_float4(o[0], o[1], o[2], o[3]);
            *reinterpret_cast<float4*>((float*)outf + (size_t)n * DD + d) = ov;
        }
    }
}

extern "C" void kernel_launch(void* const* d_in, const int* in_sizes, int n_in,
                              void* d_out, int out_size, void* d_ws, size_t ws_size,
                              hipStream_t stream)
{
    const int N = NN, E = EE;
    const float* x_in      = (const float*)d_in[0];
    const float* edge_attr = (const float*)d_in[1];
    const float* Wck = (const float*)d_in[2];
    const float* bck = (const float*)d_in[3];
    const float* Wq  = (const float*)d_in[4];
    const float* bq  = (const float*)d_in[5];
    const float* Wv  = (const float*)d_in[6];
    const float* bv  = (const float*)d_in[7];
    const float* Waw = (const float*)d_in[8];
    const float* baw = (const float*)d_in[9];
    const float* Wc  = (const float*)d_in[10];
    const float* bc  = (const float*)d_in[11];
    const float* Wlx = (const float*)d_in[12];
    const float* blx = (const float*)d_in[13];
    const float* Wla1 = (const float*)d_in[14];
    const float* bla1 = (const float*)d_in[15];
    const float* Wla2 = (const float*)d_in[16];
    const float* bla2 = (const float*)d_in[17];
    const int* eidx = (const int*)d_in[18];
    const int* srcp = eidx;       // edge_index[0]
    const int* dstp = eidx + E;   // edge_index[1]

    const size_t DDDD = (size_t)DD * DD;
    float* p = (float*)d_ws;
    const size_t NB = (size_t)N * DD;
    float* degf  = p; p += N;
    float* wfx32 = p; p += NL * DDDD;
    float* bfbuf = p; p += NL * DD;
    float* bqkvb = p; p += NL * 3 * DD;
    // int region
    int* rowptr = (int*)p;
    int* cursor = rowptr + (N + 1);
    int* perm   = cursor + N;
    int* src_s  = perm + E;
    p += (size_t)(2 * N + 1 + 2 * E + 63) / 64 * 64;
    // bf16 regions (counted in floats = elems/2)
    unsigned short* xb16  = (unsigned short*)p; p += NB / 2;
    unsigned short* hb16  = (unsigned short*)p; p += NB / 2;
    unsigned short* agg16 = (unsigned short*)p; p += NB / 2;
    unsigned short* qkv16 = (unsigned short*)p; p += 3 * NB / 2;   // [N][2304]
    unsigned short* ea16  = (unsigned short*)p; p += (size_t)E * DD / 2;
    unsigned short* kea16 = (unsigned short*)p; p += (size_t)E * DD / 2;
    unsigned short* gb16  = qkv16;                 // reuse after edge_fused
    // weights (all NL layers)
    unsigned short* wqkvt  = (unsigned short*)p; p += NL * 3 * DDDD / 2; // [l][2304][768]
    unsigned short* wcktopt= (unsigned short*)p; p += NL * DDDD / 2;
    unsigned short* wct    = (unsigned short*)p; p += NL * DDDD / 2;
    unsigned short* wla1tt = (unsigned short*)p; p += NL * DDDD / 2;
    unsigned short* wst3   = (unsigned short*)p; p += NL * 2 * DDDD / 2; // [l][768][1536]
    unsigned short* wlx16  = (unsigned short*)p; p += NL * DDDD / 2;

    // ================= setup (once) =================
    hipMemsetAsync(cursor, 0, N * sizeof(int), stream);
    deg_kernel<<<(E + 255) / 256, 256, 0, stream>>>(dstp, cursor);
    scan_kernel<<<1, 256, 0, stream>>>(cursor, rowptr, cursor);
    fill_perm<<<(E + 255) / 256, 256, 0, stream>>>(srcp, dstp, cursor, perm, src_s);
    degf_kernel<<<(N + 255) / 256, 256, 0, stream>>>(rowptr, degf);
    f2b_gather<<<(E * 96 + 255) / 256, 256, 0, stream>>>(edge_attr, perm, ea16);
    f2b_kernel<<<(N * 96 + 255) / 256, 256, 0, stream>>>(x_in, xb16, N * 96);

    // ---- batched weight prep (z = layer) ----
    dim3 gt3(DD / 32, DD / 32, NL);
    transpose_w<<<gt3, 256, 0, stream>>>(Wq, wqkvt, DD, DD, 0, DDDD, 3 * DDDD);
    transpose_w<<<gt3, 256, 0, stream>>>(Wck + DDDD, wqkvt + DDDD, DD, DD, 0, 2 * DDDD, 3 * DDDD);
    transpose_w<<<gt3, 256, 0, stream>>>(Wv, wqkvt + 2 * DDDD, DD, DD, 0, DDDD, 3 * DDDD);
    transpose_w<<<gt3, 256, 0, stream>>>(Wck, wcktopt, DD, DD, 0, 2 * DDDD, DDDD);
    transpose_w<<<gt3, 256, 0, stream>>>(Wc, wct, DD, DD, 0, DDDD, DDDD);
    transpose_w<<<gt3, 256, 0, stream>>>(Wla1, wla1tt, DD, DD, 0, 2 * DDDD, DDDD);
    transpose_w<<<gt3, 256, 0, stream>>>(Wla1 + DDDD, wst3, DD, 2 * DD, DD, 2 * DDDD, 2 * DDDD);
    f2b_kernel<<<(NL * DD * 96 + 255) / 256, 256, 0, stream>>>(Wlx, wlx16, NL * DD * 96);
    // wfx[l] = Wlx[l] @ Wla1_top[l]  (batched z=NL)
    gemm_mfma<<<dim3(6, 3, NL), 512, 0, stream>>>(wlx16, nullptr, wla1tt, nullptr, nullptr,
                                                  wfx32, nullptr, DD, DD, DD,
                                                  DDDD, DDDD, DDDD);
    transpose_w<<<gt3, 256, 0, stream>>>(wfx32, wst3, DD, 2 * DD, 0, DDDD, 2 * DDDD);
    biasf_kernel<<<dim3(3, NL), 256, 0, stream>>>(blx, Wla1, bla1, bfbuf);
    biasqkv_kernel<<<dim3(9, NL), 256, 0, stream>>>(bq, bv, bqkvb);

    // ================= layer loop =================
    for (int l = 0; l < NL; l++) {
        const float* bck_l = bck + (size_t)l * DD;
        const float* Waw_l = Waw + (size_t)l * HH * HH;
        const float* baw_l = baw + (size_t)l * HH;
        const float* bc_l  = bc  + (size_t)l * DD;
        const float* Wla2_l = Wla2 + (size_t)l * DD * 2;
        const float* bla2_l = bla2 + (size_t)l * 2;

        // ---- qkv node GEMM [N][2304] ----
        gemm_mfma<<<dim3(18, (N + 255) / 256), 512, 0, stream>>>(
            xb16, nullptr, wqkvt + (size_t)l * 3 * DDDD, bqkvb + (size_t)l * 3 * DD,
            nullptr, nullptr, qkv16, N, DD, 3 * DD, 0, 0, 0);
        // ---- kea edge GEMM [E][768] ----
        gemm_mfma<<<dim3(6, (E + 255) / 256), 512, 0, stream>>>(
            ea16, nullptr, wcktopt + (size_t)l * DDDD, bck_l,
            nullptr, nullptr, kea16, E, DD, DD, 0, 0, 0);
        // ---- fused attention + aggregation (single pass) ----
        edge_fused<<<N, 128, 0, stream>>>(kea16, qkv16, Waw_l, baw_l, rowptr, src_s, agg16);
        // ---- h = agg @ Wc + deg*bc (bf16 out) ----
        gemm_mfma<<<dim3(6, (N + 255) / 256), 512, 0, stream>>>(
            agg16, nullptr, wct + (size_t)l * DDDD, bc_l,
            degf, nullptr, hb16, N, DD, DD, 0, 0, 0);
        // ---- g = x@Wfx + h@Wla1_bot + bf ----
        gemm_mfma<<<dim3(6, (N + 255) / 256), 512, 0, stream>>>(
            xb16, hb16, wst3 + (size_t)l * 2 * DDDD, bfbuf + (size_t)l * DD,
            nullptr, nullptr, gb16, N, 2 * DD, DD, 0, 0, 0);
        // ---- gated combine ----
        combine_kernel<<<(N + 3) / 4, 256, 0, stream>>>(
            gb16, Wla2_l, bla2_l, xb16, hb16,
            (l == NL - 1) ? (float*)d_out : nullptr, N);
    }
}

// Round 12
// 1953.561 us; speedup vs baseline: 1.0219x; 1.0219x over previous
//
#include <hip/hip_runtime.h>
#include <hip/hip_bf16.h>
#include <math.h>

#define DD 768
#define HH 8
#define DHH 96
#define NL 3
#define NN 20000
#define EE 100000

typedef __attribute__((ext_vector_type(8))) __bf16 bf16x8;
typedef __attribute__((ext_vector_type(4))) float f32x4;
typedef __attribute__((ext_vector_type(8))) unsigned short u16x8;

__host__ __device__ static inline int imin(int a, int b) { return a < b ? a : b; }

__device__ inline float b2f(unsigned short u) {
    union { unsigned int v; float f; } x; x.v = ((unsigned int)u) << 16; return x.f;
}
__device__ inline unsigned short f2b_rne(float f) {
    union { float f; unsigned int v; } x; x.f = f;
    unsigned int v = x.v;
    return (unsigned short)((v + 0x7FFFu + ((v >> 16) & 1u)) >> 16);
}
__device__ inline void b2f2(unsigned int u, float& lo, float& hi) {
    union { unsigned int v; float f; } x;
    x.v = u << 16; lo = x.f;
    x.v = u & 0xffff0000u; hi = x.f;
}
__device__ inline unsigned int packbf(float a, float b) {
    return (unsigned int)f2b_rne(a) | ((unsigned int)f2b_rne(b) << 16);
}

// ================= CSR build =================
__global__ void deg_kernel(const int* __restrict__ dst, int* __restrict__ cnt)
{
    int i = blockIdx.x * 256 + threadIdx.x;
    if (i < EE) atomicAdd(&cnt[dst[i]], 1);
}

__global__ __launch_bounds__(256)
void scan_kernel(const int* __restrict__ deg, int* __restrict__ rowptr, int* __restrict__ cursor)
{
    __shared__ int part[256];
    int t = threadIdx.x;
    const int per = (NN + 255) / 256;
    int lo = t * per, hi = imin(NN, lo + per);
    int s = 0;
    for (int i = lo; i < hi; i++) s += deg[i];
    part[t] = s;
    __syncthreads();
    if (t == 0) {
        int acc = 0;
        for (int i = 0; i < 256; i++) { int v = part[i]; part[i] = acc; acc += v; }
        rowptr[NN] = acc;
    }
    __syncthreads();
    int run = part[t];
    for (int i = lo; i < hi; i++) {
        rowptr[i] = run; cursor[i] = run;
        run += deg[i];
    }
}

__global__ void fill_perm(const int* __restrict__ src, const int* __restrict__ dst,
                          int* __restrict__ cursor, int* __restrict__ perm,
                          int* __restrict__ src_s)
{
    int e = blockIdx.x * 256 + threadIdx.x;
    if (e >= EE) return;
    int d = dst[e];
    int pos = atomicAdd(&cursor[d], 1);
    perm[pos] = e;
    src_s[pos] = src[e];
}

__global__ void degf_kernel(const int* __restrict__ rowptr, float* __restrict__ degf)
{
    int n = blockIdx.x * 256 + threadIdx.x;
    if (n < NN) degf[n] = (float)(rowptr[n + 1] - rowptr[n]);
}

// ================= conversions =================
__global__ void f2b_kernel(const float* __restrict__ in, unsigned short* __restrict__ out, int n8)
{
    int i = blockIdx.x * 256 + threadIdx.x;
    if (i >= n8) return;
    const float4* p = reinterpret_cast<const float4*>(in + (size_t)i * 8);
    float4 a = p[0], b = p[1];
    u16x8 o;
    o[0] = f2b_rne(a.x); o[1] = f2b_rne(a.y); o[2] = f2b_rne(a.z); o[3] = f2b_rne(a.w);
    o[4] = f2b_rne(b.x); o[5] = f2b_rne(b.y); o[6] = f2b_rne(b.z); o[7] = f2b_rne(b.w);
    *reinterpret_cast<u16x8*>(out + (size_t)i * 8) = o;
}

__global__ void f2b_gather(const float* __restrict__ in, const int* __restrict__ perm,
                           unsigned short* __restrict__ out)
{
    int i = blockIdx.x * 256 + threadIdx.x;
    if (i >= EE * 96) return;
    int m = i / 96;
    int d8 = (i % 96) * 8;
    int row = perm[m];
    const float4* p = reinterpret_cast<const float4*>(in + (size_t)row * DD + d8);
    float4 a = p[0], b = p[1];
    u16x8 o;
    o[0] = f2b_rne(a.x); o[1] = f2b_rne(a.y); o[2] = f2b_rne(a.z); o[3] = f2b_rne(a.w);
    o[4] = f2b_rne(b.x); o[5] = f2b_rne(b.y); o[6] = f2b_rne(b.z); o[7] = f2b_rne(b.w);
    *reinterpret_cast<u16x8*>(out + (size_t)m * DD + d8) = o;
}

// ---- W [Kin][768] fp32 -> Wt[n*out_ld + out_off + k] bf16 ; z-batched ----
__global__ void transpose_w(const float* __restrict__ W, unsigned short* __restrict__ Wt,
                            int Kin, int out_ld, int out_off,
                            size_t strideW, size_t strideWt)
{
    __shared__ float tile[32][33];
    int z = blockIdx.z;
    W  += (size_t)z * strideW;
    Wt += (size_t)z * strideWt;
    int kb = blockIdx.x * 32, nb = blockIdx.y * 32;
    int tx = threadIdx.x & 31, ty = threadIdx.x >> 5;
#pragma unroll
    for (int i = 0; i < 32; i += 8)
        tile[ty + i][tx] = W[(size_t)(kb + ty + i) * DD + nb + tx];
    __syncthreads();
#pragma unroll
    for (int i = 0; i < 32; i += 8)
        Wt[(size_t)(nb + ty + i) * out_ld + out_off + kb + tx] = f2b_rne(tile[tx][ty + i]);
}

// bf[l][n] = bla1[l][n] + sum_k blx[l][k] * Wla1_top[l][k][n]   (grid: (3, NL))
__global__ void biasf_kernel(const float* __restrict__ blx, const float* __restrict__ Wla1,
                             const float* __restrict__ bla1, float* __restrict__ bf)
{
    int l = blockIdx.y;
    const float* blxl  = blx  + (size_t)l * DD;
    const float* Wla1l = Wla1 + (size_t)l * 2 * DD * DD;
    const float* bla1l = bla1 + (size_t)l * DD;
    float* bfl = bf + (size_t)l * DD;
    int n = blockIdx.x * 256 + threadIdx.x;
    if (n >= DD) return;
    float s = bla1l[n];
    for (int k = 0; k < DD; k++) s += blxl[k] * Wla1l[(size_t)k * DD + n];
    bfl[n] = s;
}

// grid (9, NL)
__global__ void biasqkv_kernel(const float* __restrict__ bq, const float* __restrict__ bv,
                               float* __restrict__ bqkv)
{
    int l = blockIdx.y;
    int i = blockIdx.x * 256 + threadIdx.x;
    if (i >= 3 * DD) return;
    float v = 0.f;
    if (i < DD) v = bq[(size_t)l * DD + i];
    else if (i >= 2 * DD) v = bv[(size_t)l * DD + i - 2 * DD];
    bqkv[(size_t)l * 3 * DD + i] = v;
}

// ================= MFMA GEMM =================
// C[M,Nw] = concat(A0,A1)[M,K] @ W + bias*rowscale ; Wt [Nw][K] bf16 n-major.
// 256x128 tile, 8 waves, BK=64. Double-buffered with COUNTED vmcnt pipeline:
//   STAGE(next) -> s_waitcnt vmcnt(6) (prev tile landed; new 6 stay in flight
//   ACROSS the barrier) -> raw s_barrier -> MFMA -> raw s_barrier.
// Load count is UNIFORM (M-edge rows clamp, not skip) so per-wave vmcnt works.
__global__ __launch_bounds__(512, 2)
void gemm_mfma(const unsigned short* __restrict__ A0,
               const unsigned short* __restrict__ A1,
               const unsigned short* __restrict__ Wt,
               const float* __restrict__ bias,
               const float* __restrict__ rowscale,
               float* __restrict__ C32,
               unsigned short* __restrict__ C16,
               int M, int K, int Nw,
               size_t bsA, size_t bsW, size_t bsC)
{
    __shared__ __align__(16) char smem[98304];   // 2 x (As 32KB + Bs 16KB)
    const int z = blockIdx.z;
    A0 += (size_t)z * bsA;
    Wt += (size_t)z * bsW;
    if (C32) C32 += (size_t)z * bsC;
    if (C16) C16 += (size_t)z * bsC;
    const int t = threadIdx.x;
    const int l = t & 63;
    const int w = t >> 6;            // wave 0..7
    const int wm = w & 3, wn = w >> 2;

    // ---- XCD-chunked bijective swizzle (m204) ----
    const int gx = gridDim.x;
    const int nwg = gx * gridDim.y;
    const int lin = blockIdx.y * gx + blockIdx.x;
    const int xcd = lin & 7, pos = lin >> 3;
    const int q8 = nwg >> 3, r8 = nwg & 7;
    const int base = (xcd < r8) ? xcd * (q8 + 1) : r8 * (q8 + 1) + (xcd - r8) * q8;
    const int swz = base + pos;
    const int bn = swz % gx, bm = swz / gx;

    const int srow = t >> 3;                      // 0..63
    const int ssrc = ((t & 7) ^ (srow & 7)) * 8;  // swizzled source col (bf16)

    const int lane_r = l & 15;
    const int lane_k = l >> 4;

    // stage one K-step (BK=64) into buffer `buf` — 6 gload_lds per thread, ALWAYS
    auto STAGE = [&](int buf, int k0) {
        char* As = smem + buf * 49152;
        char* Bs = As + 32768;
        const unsigned short* Ap; int kbase;
        if (k0 < DD) { Ap = A0; kbase = k0; }
        else         { Ap = A1; kbase = k0 - DD; }
#pragma unroll
        for (int i = 0; i < 4; i++) {
            int grow = bm * 256 + i * 64 + srow;
            if (grow >= M) grow = M - 1;          // clamp (uniform load count)
            char* ldstA = As + ((i * 64 + w * 8) << 7);
            const unsigned short* g = Ap + (size_t)grow * DD + kbase + ssrc;
            __builtin_amdgcn_global_load_lds(
                (const __attribute__((address_space(1))) void*)g,
                (__attribute__((address_space(3))) void*)ldstA, 16, 0, 0);
        }
#pragma unroll
        for (int i = 0; i < 2; i++) {
            int gn = bn * 128 + i * 64 + srow;
            const unsigned short* gB = Wt + (size_t)gn * K + k0 + ssrc;
            char* ldstB = Bs + ((i * 64 + w * 8) << 7);
            __builtin_amdgcn_global_load_lds(
                (const __attribute__((address_space(1))) void*)gB,
                (__attribute__((address_space(3))) void*)ldstB, 16, 0, 0);
        }
    };

    f32x4 acc[4][4];
#pragma unroll
    for (int m = 0; m < 4; m++)
#pragma unroll
        for (int n = 0; n < 4; n++) acc[m][n] = (f32x4){0.f, 0.f, 0.f, 0.f};

    const int nt = K >> 6;
    STAGE(0, 0);
    int cur = 0;
    for (int tt = 0; tt < nt; tt++) {
        if (tt + 1 < nt) {
            STAGE(cur ^ 1, (tt + 1) << 6);        // 6 new loads in flight
            asm volatile("s_waitcnt vmcnt(6)" ::: "memory");   // prev tile landed
        } else {
            asm volatile("s_waitcnt vmcnt(0)" ::: "memory");
        }
        __builtin_amdgcn_s_barrier();             // whole tile visible (raw: no drain)
        __builtin_amdgcn_sched_barrier(0);        // pin ds_reads after barrier
        char* As = smem + cur * 49152;
        char* Bs = As + 32768;
        __builtin_amdgcn_s_setprio(1);
#pragma unroll
        for (int kk = 0; kk < 2; kk++) {
            bf16x8 af[4], bfr[4];
#pragma unroll
            for (int m = 0; m < 4; m++) {
                int r = wm * 64 + m * 16 + lane_r;
                int slot = (kk * 4 + lane_k) ^ (r & 7);
                af[m] = *reinterpret_cast<const bf16x8*>(As + r * 128 + slot * 16);
            }
#pragma unroll
            for (int n = 0; n < 4; n++) {
                int r = wn * 64 + n * 16 + lane_r;
                int slot = (kk * 4 + lane_k) ^ (r & 7);
                bfr[n] = *reinterpret_cast<const bf16x8*>(Bs + r * 128 + slot * 16);
            }
#pragma unroll
            for (int m = 0; m < 4; m++)
#pragma unroll
                for (int n = 0; n < 4; n++)
                    acc[m][n] = __builtin_amdgcn_mfma_f32_16x16x32_bf16(
                        af[m], bfr[n], acc[m][n], 0, 0, 0);
        }
        __builtin_amdgcn_s_setprio(0);
        asm volatile("s_waitcnt lgkmcnt(0)" ::: "memory");  // all ds_reads of buf[cur] done
        __builtin_amdgcn_sched_barrier(0);
        __builtin_amdgcn_s_barrier();             // safe to overwrite buf[cur] next iter
        cur ^= 1;
    }

    // ---- fp32 direct path ----
    if (C32) {
#pragma unroll
        for (int n = 0; n < 4; n++) {
            int col = bn * 128 + wn * 64 + n * 16 + lane_r;
            float badd = bias ? bias[col] : 0.f;
#pragma unroll
            for (int m = 0; m < 4; m++) {
#pragma unroll
                for (int j = 0; j < 4; j++) {
                    int r = bm * 256 + wm * 64 + m * 16 + lane_k * 4 + j;
                    if (r < M) {
                        float bs = rowscale ? rowscale[r] : 1.f;
                        C32[(size_t)r * Nw + col] = acc[m][n][j] + badd * bs;
                    }
                }
            }
        }
    }
    // ---- bf16 path: one 256x136 padded staging tile ----
    if (C16) {
        unsigned short* cs = (unsigned short*)smem;
#pragma unroll
        for (int n = 0; n < 4; n++) {
            int lcol = wn * 64 + n * 16 + lane_r;
            float badd = bias ? bias[bn * 128 + lcol] : 0.f;
#pragma unroll
            for (int m = 0; m < 4; m++) {
#pragma unroll
                for (int j = 0; j < 4; j++) {
                    int lr = wm * 64 + m * 16 + lane_k * 4 + j;     // 0..255
                    int r = bm * 256 + lr;
                    float bs = rowscale ? (r < M ? rowscale[r] : 0.f) : 1.f;
                    cs[lr * 136 + lcol] = f2b_rne(acc[m][n][j] + badd * bs);
                }
            }
        }
        __syncthreads();
        // 512 threads over 256 rows x 128 cols: 2 threads/row, 64 cols = 8 u16x8 each
        int rr = t >> 1, half = t & 1;
        int grow = bm * 256 + rr;
        if (grow < M) {
            u16x8* dst = reinterpret_cast<u16x8*>(C16 + (size_t)grow * Nw + bn * 128 + half * 64);
            const u16x8* s = reinterpret_cast<const u16x8*>(cs + rr * 136 + half * 64);
#pragma unroll
            for (int c = 0; c < 8; c++) dst[c] = s[c];
        }
    }
}

// ================= fused edge attention + aggregation =================
__global__ __launch_bounds__(128)
void edge_fused(const unsigned short* __restrict__ kea,
                const unsigned short* __restrict__ qkv,
                const float* __restrict__ Waw, const float* __restrict__ baw,
                const int* __restrict__ rowptr, const int* __restrict__ src_s,
                unsigned short* __restrict__ agg)
{
    __shared__ float awsh[HH];
    __shared__ float WawS[HH * HH];
    __shared__ float bawS[HH];
    const int n = blockIdx.x;
    const int t = threadIdx.x;      // 0..127, 6 features each
    const int d0 = t * 6;
    const int h = t >> 4;           // 16 threads per head
    if (t < HH * HH) WawS[t] = Waw[t];
    if (t < HH) bawS[t] = baw[t];
    const int jlo = rowptr[n], jhi = rowptr[n + 1];
    const unsigned int* qr = reinterpret_cast<const unsigned int*>(qkv + (size_t)n * (3 * DD) + d0);
    float q[6];
    b2f2(qr[0], q[0], q[1]); b2f2(qr[1], q[2], q[3]); b2f2(qr[2], q[4], q[5]);
    float acc[6] = {0.f, 0.f, 0.f, 0.f, 0.f, 0.f};
    float sa = 0.f;
    constexpr float rs = 0.03608439182435161f; // 1/sqrt(768)
    __syncthreads();
    for (int j = jlo; j < jhi; j++) {
        int s = src_s[j];
        const unsigned int* ke = reinterpret_cast<const unsigned int*>(kea + (size_t)j * DD + d0);
        const unsigned int* kr = reinterpret_cast<const unsigned int*>(qkv + (size_t)s * (3 * DD) + DD + d0);
        const unsigned int* vr = reinterpret_cast<const unsigned int*>(qkv + (size_t)s * (3 * DD) + 2 * DD + d0);
        float part = 0.f;
        float ka, kb2, va, vb;
#pragma unroll
        for (int c = 0; c < 3; c++) {
            b2f2(ke[c], ka, kb2);
            b2f2(kr[c], va, vb);
            part = fmaf(q[2 * c], ka + va, part);
            part = fmaf(q[2 * c + 1], kb2 + vb, part);
        }
        part += __shfl_xor(part, 1);
        part += __shfl_xor(part, 2);
        part += __shfl_xor(part, 4);
        part += __shfl_xor(part, 8);
        if ((t & 15) == 0) awsh[h] = part;
        __syncthreads();
        float zz = bawS[h];
#pragma unroll
        for (int h2 = 0; h2 < HH; h2++) {
            float aw = awsh[h2] * rs;
            float tt = aw > 0.f ? aw : 0.2f * aw;
            zz = fmaf(tt, WawS[h2 * HH + h], zz);
        }
        float a = expf(zz);
        sa += a;
        float v0, v1;
#pragma unroll
        for (int c = 0; c < 3; c++) {
            b2f2(vr[c], v0, v1);
            acc[2 * c]     = fmaf(a, v0, acc[2 * c]);
            acc[2 * c + 1] = fmaf(a, v1, acc[2 * c + 1]);
        }
        __syncthreads();
    }
    float inv = (sa == 0.f) ? 1.f : 1.f / sa;
    unsigned int* ag = reinterpret_cast<unsigned int*>(agg + (size_t)n * DD + d0);
    ag[0] = packbf(acc[0] * inv, acc[1] * inv);
    ag[1] = packbf(acc[2] * inv, acc[3] * inv);
    ag[2] = packbf(acc[4] * inv, acc[5] * inv);
}

// one wave per node: z = lrelu(g)@Wla2 + bla2 ; la = softmax(z) ; out = x*la0 + h*la1
__global__ __launch_bounds__(256)
void combine_kernel(const unsigned short* __restrict__ g, const float* __restrict__ Wla2,
                    const float* __restrict__ bla2, unsigned short* __restrict__ x16,
                    const unsigned short* __restrict__ h, float* __restrict__ outf, int Nn)
{
    int w = threadIdx.x >> 6;
    int lane = threadIdx.x & 63;
    int n = blockIdx.x * 4 + w;
    if (n >= Nn) return;
    float z0 = 0.f, z1 = 0.f;
#pragma unroll
    for (int p = 0; p < 3; p++) {
        int d = p * 256 + lane * 4;
        const unsigned short* gp = g + (size_t)n * DD + d;
#pragma unroll
        for (int j = 0; j < 4; j++) {
            float gv = b2f(gp[j]);
            float tt = gv > 0.f ? gv : 0.2f * gv;
            z0 = fmaf(tt, Wla2[(d + j) * 2 + 0], z0);
            z1 = fmaf(tt, Wla2[(d + j) * 2 + 1], z1);
        }
    }
#pragma unroll
    for (int off = 32; off > 0; off >>= 1) {
        z0 += __shfl_xor(z0, off);
        z1 += __shfl_xor(z1, off);
    }
    z0 += bla2[0]; z1 += bla2[1];
    float mx = fmaxf(z0, z1);
    float e0v = expf(z0 - mx), e1v = expf(z1 - mx);
    float inv = 1.f / (e0v + e1v);
    float la0 = e0v * inv, la1 = e1v * inv;
#pragma unroll
    for (int p = 0; p < 3; p++) {
        int d = p * 256 + lane * 4;
        unsigned short* xp = x16 + (size_t)n * DD + d;
        const unsigned short* hp = h + (size_t)n * DD + d;
        float o[4];
#pragma unroll
        for (int j = 0; j < 4; j++)
            o[j] = b2f(xp[j]) * la0 + b2f(hp[j]) * la1;
#pragma unroll
        for (int j = 0; j < 4; j++) xp[j] = f2b_rne(o[j]);
        if (outf) {
            float4 ov = make_float4(o[0], o[1], o[2], o[3]);
            *reinterpret_cast<float4*>((float*)outf + (size_t)n * DD + d) = ov;
        }
    }
}

extern "C" void kernel_launch(void* const* d_in, const int* in_sizes, int n_in,
                              void* d_out, int out_size, void* d_ws, size_t ws_size,
                              hipStream_t stream)
{
    const int N = NN, E = EE;
    const float* x_in      = (const float*)d_in[0];
    const float* edge_attr = (const float*)d_in[1];
    const float* Wck = (const float*)d_in[2];
    const float* bck = (const float*)d_in[3];
    const float* Wq  = (const float*)d_in[4];
    const float* bq  = (const float*)d_in[5];
    const float* Wv  = (const float*)d_in[6];
    const float* bv  = (const float*)d_in[7];
    const float* Waw = (const float*)d_in[8];
    const float* baw = (const float*)d_in[9];
    const float* Wc  = (const float*)d_in[10];
    const float* bc  = (const float*)d_in[11];
    const float* Wlx = (const float*)d_in[12];
    const float* blx = (const float*)d_in[13];
    const float* Wla1 = (const float*)d_in[14];
    const float* bla1 = (const float*)d_in[15];
    const float* Wla2 = (const float*)d_in[16];
    const float* bla2 = (const float*)d_in[17];
    const int* eidx = (const int*)d_in[18];
    const int* srcp = eidx;       // edge_index[0]
    const int* dstp = eidx + E;   // edge_index[1]

    const size_t DDDD = (size_t)DD * DD;
    float* p = (float*)d_ws;
    const size_t NB = (size_t)N * DD;
    float* degf  = p; p += N;
    float* wfx32 = p; p += NL * DDDD;
    float* bfbuf = p; p += NL * DD;
    float* bqkvb = p; p += NL * 3 * DD;
    // int region
    int* rowptr = (int*)p;
    int* cursor = rowptr + (N + 1);
    int* perm   = cursor + N;
    int* src_s  = perm + E;
    p += (size_t)(2 * N + 1 + 2 * E + 63) / 64 * 64;
    // bf16 regions (counted in floats = elems/2)
    unsigned short* xb16  = (unsigned short*)p; p += NB / 2;
    unsigned short* hb16  = (unsigned short*)p; p += NB / 2;
    unsigned short* agg16 = (unsigned short*)p; p += NB / 2;
    unsigned short* qkv16 = (unsigned short*)p; p += 3 * NB / 2;   // [N][2304]
    unsigned short* ea16  = (unsigned short*)p; p += (size_t)E * DD / 2;
    unsigned short* kea16 = (unsigned short*)p; p += (size_t)E * DD / 2;
    unsigned short* gb16  = qkv16;                 // reuse after edge_fused
    // weights (all NL layers)
    unsigned short* wqkvt  = (unsigned short*)p; p += NL * 3 * DDDD / 2; // [l][2304][768]
    unsigned short* wcktopt= (unsigned short*)p; p += NL * DDDD / 2;
    unsigned short* wct    = (unsigned short*)p; p += NL * DDDD / 2;
    unsigned short* wla1tt = (unsigned short*)p; p += NL * DDDD / 2;
    unsigned short* wst3   = (unsigned short*)p; p += NL * 2 * DDDD / 2; // [l][768][1536]
    unsigned short* wlx16  = (unsigned short*)p; p += NL * DDDD / 2;

    // ================= setup (once) =================
    hipMemsetAsync(cursor, 0, N * sizeof(int), stream);
    deg_kernel<<<(E + 255) / 256, 256, 0, stream>>>(dstp, cursor);
    scan_kernel<<<1, 256, 0, stream>>>(cursor, rowptr, cursor);
    fill_perm<<<(E + 255) / 256, 256, 0, stream>>>(srcp, dstp, cursor, perm, src_s);
    degf_kernel<<<(N + 255) / 256, 256, 0, stream>>>(rowptr, degf);
    f2b_gather<<<(E * 96 + 255) / 256, 256, 0, stream>>>(edge_attr, perm, ea16);
    f2b_kernel<<<(N * 96 + 255) / 256, 256, 0, stream>>>(x_in, xb16, N * 96);

    // ---- batched weight prep (z = layer) ----
    dim3 gt3(DD / 32, DD / 32, NL);
    transpose_w<<<gt3, 256, 0, stream>>>(Wq, wqkvt, DD, DD, 0, DDDD, 3 * DDDD);
    transpose_w<<<gt3, 256, 0, stream>>>(Wck + DDDD, wqkvt + DDDD, DD, DD, 0, 2 * DDDD, 3 * DDDD);
    transpose_w<<<gt3, 256, 0, stream>>>(Wv, wqkvt + 2 * DDDD, DD, DD, 0, DDDD, 3 * DDDD);
    transpose_w<<<gt3, 256, 0, stream>>>(Wck, wcktopt, DD, DD, 0, 2 * DDDD, DDDD);
    transpose_w<<<gt3, 256, 0, stream>>>(Wc, wct, DD, DD, 0, DDDD, DDDD);
    transpose_w<<<gt3, 256, 0, stream>>>(Wla1, wla1tt, DD, DD, 0, 2 * DDDD, DDDD);
    transpose_w<<<gt3, 256, 0, stream>>>(Wla1 + DDDD, wst3, DD, 2 * DD, DD, 2 * DDDD, 2 * DDDD);
    f2b_kernel<<<(NL * DD * 96 + 255) / 256, 256, 0, stream>>>(Wlx, wlx16, NL * DD * 96);
    // wfx[l] = Wlx[l] @ Wla1_top[l]  (batched z=NL)
    gemm_mfma<<<dim3(6, 3, NL), 512, 0, stream>>>(wlx16, nullptr, wla1tt, nullptr, nullptr,
                                                  wfx32, nullptr, DD, DD, DD,
                                                  DDDD, DDDD, DDDD);
    transpose_w<<<gt3, 256, 0, stream>>>(wfx32, wst3, DD, 2 * DD, 0, DDDD, 2 * DDDD);
    biasf_kernel<<<dim3(3, NL), 256, 0, stream>>>(blx, Wla1, bla1, bfbuf);
    biasqkv_kernel<<<dim3(9, NL), 256, 0, stream>>>(bq, bv, bqkvb);

    // ================= layer loop =================
    for (int l = 0; l < NL; l++) {
        const float* bck_l = bck + (size_t)l * DD;
        const float* Waw_l = Waw + (size_t)l * HH * HH;
        const float* baw_l = baw + (size_t)l * HH;
        const float* bc_l  = bc  + (size_t)l * DD;
        const float* Wla2_l = Wla2 + (size_t)l * DD * 2;
        const float* bla2_l = bla2 + (size_t)l * 2;

        // ---- qkv node GEMM [N][2304] ----
        gemm_mfma<<<dim3(18, (N + 255) / 256), 512, 0, stream>>>(
            xb16, nullptr, wqkvt + (size_t)l * 3 * DDDD, bqkvb + (size_t)l * 3 * DD,
            nullptr, nullptr, qkv16, N, DD, 3 * DD, 0, 0, 0);
        // ---- kea edge GEMM [E][768] ----
        gemm_mfma<<<dim3(6, (E + 255) / 256), 512, 0, stream>>>(
            ea16, nullptr, wcktopt + (size_t)l * DDDD, bck_l,
            nullptr, nullptr, kea16, E, DD, DD, 0, 0, 0);
        // ---- fused attention + aggregation (single pass) ----
        edge_fused<<<N, 128, 0, stream>>>(kea16, qkv16, Waw_l, baw_l, rowptr, src_s, agg16);
        // ---- h = agg @ Wc + deg*bc (bf16 out) ----
        gemm_mfma<<<dim3(6, (N + 255) / 256), 512, 0, stream>>>(
            agg16, nullptr, wct + (size_t)l * DDDD, bc_l,
            degf, nullptr, hb16, N, DD, DD, 0, 0, 0);
        // ---- g = x@Wfx + h@Wla1_bot + bf ----
        gemm_mfma<<<dim3(6, (N + 255) / 256), 512, 0, stream>>>(
            xb16, hb16, wst3 + (size_t)l * 2 * DDDD, bfbuf + (size_t)l * DD,
            nullptr, nullptr, gb16, N, 2 * DD, DD, 0, 0, 0);
        // ---- gated combine ----
        combine_kernel<<<(N + 3) / 4, 256, 0, stream>>>(
            gb16, Wla2_l, bla2_l, xb16, hb16,
            (l == NL - 1) ? (float*)d_out : nullptr, N);
    }
}

// Round 13
// 1774.718 us; speedup vs baseline: 1.1249x; 1.1008x over previous
//
#include <hip/hip_runtime.h>
#include <hip/hip_bf16.h>
#include <math.h>

#define DD 768
#define HH 8
#define DHH 96
#define NL 3
#define NN 20000
#define EE 100000

typedef __attribute__((ext_vector_type(8))) __bf16 bf16x8;
typedef __attribute__((ext_vector_type(4))) float f32x4;
typedef __attribute__((ext_vector_type(8))) unsigned short u16x8;

__host__ __device__ static inline int imin(int a, int b) { return a < b ? a : b; }

__device__ inline float b2f(unsigned short u) {
    union { unsigned int v; float f; } x; x.v = ((unsigned int)u) << 16; return x.f;
}
__device__ inline unsigned short f2b_rne(float f) {
    union { float f; unsigned int v; } x; x.f = f;
    unsigned int v = x.v;
    return (unsigned short)((v + 0x7FFFu + ((v >> 16) & 1u)) >> 16);
}
__device__ inline void b2f2(unsigned int u, float& lo, float& hi) {
    union { unsigned int v; float f; } x;
    x.v = u << 16; lo = x.f;
    x.v = u & 0xffff0000u; hi = x.f;
}
__device__ inline unsigned int packbf(float a, float b) {
    return (unsigned int)f2b_rne(a) | ((unsigned int)f2b_rne(b) << 16);
}

// ================= CSR build =================
__global__ void deg_kernel(const int* __restrict__ dst, int* __restrict__ cnt)
{
    int i = blockIdx.x * 256 + threadIdx.x;
    if (i < EE) atomicAdd(&cnt[dst[i]], 1);
}

__global__ __launch_bounds__(256)
void scan_kernel(const int* __restrict__ deg, int* __restrict__ rowptr, int* __restrict__ cursor)
{
    __shared__ int part[256];
    int t = threadIdx.x;
    const int per = (NN + 255) / 256;
    int lo = t * per, hi = imin(NN, lo + per);
    int s = 0;
    for (int i = lo; i < hi; i++) s += deg[i];
    part[t] = s;
    __syncthreads();
    if (t == 0) {
        int acc = 0;
        for (int i = 0; i < 256; i++) { int v = part[i]; part[i] = acc; acc += v; }
        rowptr[NN] = acc;
    }
    __syncthreads();
    int run = part[t];
    for (int i = lo; i < hi; i++) {
        rowptr[i] = run; cursor[i] = run;
        run += deg[i];
    }
}

__global__ void fill_perm(const int* __restrict__ src, const int* __restrict__ dst,
                          int* __restrict__ cursor, int* __restrict__ perm,
                          int* __restrict__ src_s)
{
    int e = blockIdx.x * 256 + threadIdx.x;
    if (e >= EE) return;
    int d = dst[e];
    int pos = atomicAdd(&cursor[d], 1);
    perm[pos] = e;
    src_s[pos] = src[e];
}

__global__ void degf_kernel(const int* __restrict__ rowptr, float* __restrict__ degf)
{
    int n = blockIdx.x * 256 + threadIdx.x;
    if (n < NN) degf[n] = (float)(rowptr[n + 1] - rowptr[n]);
}

// ================= conversions =================
__global__ void f2b_kernel(const float* __restrict__ in, unsigned short* __restrict__ out, int n8)
{
    int i = blockIdx.x * 256 + threadIdx.x;
    if (i >= n8) return;
    const float4* p = reinterpret_cast<const float4*>(in + (size_t)i * 8);
    float4 a = p[0], b = p[1];
    u16x8 o;
    o[0] = f2b_rne(a.x); o[1] = f2b_rne(a.y); o[2] = f2b_rne(a.z); o[3] = f2b_rne(a.w);
    o[4] = f2b_rne(b.x); o[5] = f2b_rne(b.y); o[6] = f2b_rne(b.z); o[7] = f2b_rne(b.w);
    *reinterpret_cast<u16x8*>(out + (size_t)i * 8) = o;
}

__global__ void f2b_gather(const float* __restrict__ in, const int* __restrict__ perm,
                           unsigned short* __restrict__ out)
{
    int i = blockIdx.x * 256 + threadIdx.x;
    if (i >= EE * 96) return;
    int m = i / 96;
    int d8 = (i % 96) * 8;
    int row = perm[m];
    const float4* p = reinterpret_cast<const float4*>(in + (size_t)row * DD + d8);
    float4 a = p[0], b = p[1];
    u16x8 o;
    o[0] = f2b_rne(a.x); o[1] = f2b_rne(a.y); o[2] = f2b_rne(a.z); o[3] = f2b_rne(a.w);
    o[4] = f2b_rne(b.x); o[5] = f2b_rne(b.y); o[6] = f2b_rne(b.z); o[7] = f2b_rne(b.w);
    *reinterpret_cast<u16x8*>(out + (size_t)m * DD + d8) = o;
}

// ---- W [Kin][768] fp32 -> Wt[n*out_ld + out_off + k] bf16 ; z-batched ----
__global__ void transpose_w(const float* __restrict__ W, unsigned short* __restrict__ Wt,
                            int Kin, int out_ld, int out_off,
                            size_t strideW, size_t strideWt)
{
    __shared__ float tile[32][33];
    int z = blockIdx.z;
    W  += (size_t)z * strideW;
    Wt += (size_t)z * strideWt;
    int kb = blockIdx.x * 32, nb = blockIdx.y * 32;
    int tx = threadIdx.x & 31, ty = threadIdx.x >> 5;
#pragma unroll
    for (int i = 0; i < 32; i += 8)
        tile[ty + i][tx] = W[(size_t)(kb + ty + i) * DD + nb + tx];
    __syncthreads();
#pragma unroll
    for (int i = 0; i < 32; i += 8)
        Wt[(size_t)(nb + ty + i) * out_ld + out_off + kb + tx] = f2b_rne(tile[tx][ty + i]);
}

// bf[l][n] = bla1[l][n] + sum_k blx[l][k] * Wla1_top[l][k][n]   (grid: (3, NL))
__global__ void biasf_kernel(const float* __restrict__ blx, const float* __restrict__ Wla1,
                             const float* __restrict__ bla1, float* __restrict__ bf)
{
    int l = blockIdx.y;
    const float* blxl  = blx  + (size_t)l * DD;
    const float* Wla1l = Wla1 + (size_t)l * 2 * DD * DD;
    const float* bla1l = bla1 + (size_t)l * DD;
    float* bfl = bf + (size_t)l * DD;
    int n = blockIdx.x * 256 + threadIdx.x;
    if (n >= DD) return;
    float s = bla1l[n];
    for (int k = 0; k < DD; k++) s += blxl[k] * Wla1l[(size_t)k * DD + n];
    bfl[n] = s;
}

// grid (9, NL)
__global__ void biasqkv_kernel(const float* __restrict__ bq, const float* __restrict__ bv,
                               float* __restrict__ bqkv)
{
    int l = blockIdx.y;
    int i = blockIdx.x * 256 + threadIdx.x;
    if (i >= 3 * DD) return;
    float v = 0.f;
    if (i < DD) v = bq[(size_t)l * DD + i];
    else if (i >= 2 * DD) v = bv[(size_t)l * DD + i - 2 * DD];
    bqkv[(size_t)l * 3 * DD + i] = v;
}

// ================= MFMA GEMM =================
// C[M,Nw] = concat(A0,A1)[M,K] @ W + bias*rowscale ; Wt [Nw][K] bf16 n-major.
// 256x128 tile, 8 waves, BK=64, single-buffered (R9-proven: 48KB LDS, ~41% occ).
// XCD-chunked bijective swizzle; z-batched; bf16 C via padded LDS staging (2 halves).
__global__ __launch_bounds__(512, 4)
void gemm_mfma(const unsigned short* __restrict__ A0,
               const unsigned short* __restrict__ A1,
               const unsigned short* __restrict__ Wt,
               const float* __restrict__ bias,
               const float* __restrict__ rowscale,
               float* __restrict__ C32,
               unsigned short* __restrict__ C16,
               int M, int K, int Nw,
               size_t bsA, size_t bsW, size_t bsC)
{
    __shared__ __align__(16) char smem[49152];   // As 32KB + Bs 16KB
    char* As = smem;
    char* Bs = smem + 32768;
    const int z = blockIdx.z;
    A0 += (size_t)z * bsA;
    Wt += (size_t)z * bsW;
    if (C32) C32 += (size_t)z * bsC;
    if (C16) C16 += (size_t)z * bsC;
    const int t = threadIdx.x;
    const int l = t & 63;
    const int w = t >> 6;            // wave 0..7
    const int wm = w & 3, wn = w >> 2;

    // ---- XCD-chunked bijective swizzle (m204) ----
    const int gx = gridDim.x;
    const int nwg = gx * gridDim.y;
    const int lin = blockIdx.y * gx + blockIdx.x;
    const int xcd = lin & 7, pos = lin >> 3;
    const int q8 = nwg >> 3, r8 = nwg & 7;
    const int base = (xcd < r8) ? xcd * (q8 + 1) : r8 * (q8 + 1) + (xcd - r8) * q8;
    const int swz = base + pos;
    const int bn = swz % gx, bm = swz / gx;

    const int srow = t >> 3;                      // 0..63
    const int ssrc = ((t & 7) ^ (srow & 7)) * 8;  // swizzled source col (bf16)

    const int lane_r = l & 15;
    const int lane_k = l >> 4;

    f32x4 acc[4][4];
#pragma unroll
    for (int m = 0; m < 4; m++)
#pragma unroll
        for (int n = 0; n < 4; n++) acc[m][n] = (f32x4){0.f, 0.f, 0.f, 0.f};

    for (int k0 = 0; k0 < K; k0 += 64) {
        const unsigned short* Ap; int kbase;
        if (k0 < DD) { Ap = A0; kbase = k0; }
        else         { Ap = A1; kbase = k0 - DD; }
#pragma unroll
        for (int i = 0; i < 4; i++) {
            int grow = bm * 256 + i * 64 + srow;
            char* ldstA = As + ((i * 64 + w * 8) << 7);
            if (grow < M) {
                const unsigned short* g = Ap + (size_t)grow * DD + kbase + ssrc;
                __builtin_amdgcn_global_load_lds(
                    (const __attribute__((address_space(1))) void*)g,
                    (__attribute__((address_space(3))) void*)ldstA, 16, 0, 0);
            }
        }
#pragma unroll
        for (int i = 0; i < 2; i++) {
            int gn = bn * 128 + i * 64 + srow;
            const unsigned short* gB = Wt + (size_t)gn * K + k0 + ssrc;
            char* ldstB = Bs + ((i * 64 + w * 8) << 7);
            __builtin_amdgcn_global_load_lds(
                (const __attribute__((address_space(1))) void*)gB,
                (__attribute__((address_space(3))) void*)ldstB, 16, 0, 0);
        }
        __syncthreads();
#pragma unroll
        for (int kk = 0; kk < 2; kk++) {
            bf16x8 af[4], bfr[4];
#pragma unroll
            for (int m = 0; m < 4; m++) {
                int r = wm * 64 + m * 16 + lane_r;
                int slot = (kk * 4 + lane_k) ^ (r & 7);
                af[m] = *reinterpret_cast<const bf16x8*>(As + r * 128 + slot * 16);
            }
#pragma unroll
            for (int n = 0; n < 4; n++) {
                int r = wn * 64 + n * 16 + lane_r;
                int slot = (kk * 4 + lane_k) ^ (r & 7);
                bfr[n] = *reinterpret_cast<const bf16x8*>(Bs + r * 128 + slot * 16);
            }
#pragma unroll
            for (int m = 0; m < 4; m++)
#pragma unroll
                for (int n = 0; n < 4; n++)
                    acc[m][n] = __builtin_amdgcn_mfma_f32_16x16x32_bf16(
                        af[m], bfr[n], acc[m][n], 0, 0, 0);
        }
        __syncthreads();
    }

    // ---- fp32 direct path ----
    if (C32) {
#pragma unroll
        for (int n = 0; n < 4; n++) {
            int col = bn * 128 + wn * 64 + n * 16 + lane_r;
            float badd = bias ? bias[col] : 0.f;
#pragma unroll
            for (int m = 0; m < 4; m++) {
#pragma unroll
                for (int j = 0; j < 4; j++) {
                    int r = bm * 256 + wm * 64 + m * 16 + lane_k * 4 + j;
                    if (r < M) {
                        float bs = rowscale ? rowscale[r] : 1.f;
                        C32[(size_t)r * Nw + col] = acc[m][n][j] + badd * bs;
                    }
                }
            }
        }
    }
    // ---- bf16 path via padded LDS staging, two 128-row halves ----
    if (C16) {
        unsigned short* cs = (unsigned short*)smem;   // stride 136 bf16 (272B rows)
#pragma unroll
        for (int half = 0; half < 2; half++) {
            __syncthreads();
            if ((wm >> 1) == half) {
#pragma unroll
                for (int n = 0; n < 4; n++) {
                    int lcol = wn * 64 + n * 16 + lane_r;
                    float badd = bias ? bias[bn * 128 + lcol] : 0.f;
#pragma unroll
                    for (int m = 0; m < 4; m++) {
#pragma unroll
                        for (int j = 0; j < 4; j++) {
                            int lr = (wm & 1) * 64 + m * 16 + lane_k * 4 + j;
                            int r = bm * 256 + half * 128 + lr;
                            float bs = rowscale ? (r < M ? rowscale[r] : 0.f) : 1.f;
                            cs[lr * 136 + lcol] = f2b_rne(acc[m][n][j] + badd * bs);
                        }
                    }
                }
            }
            __syncthreads();
            int rr = t >> 2, qd = (t & 3) * 32;      // 4 threads/row, 32 cols each
            int grow = bm * 256 + half * 128 + rr;
            if (grow < M) {
                u16x8* dst = reinterpret_cast<u16x8*>(C16 + (size_t)grow * Nw + bn * 128 + qd);
                const u16x8* s = reinterpret_cast<const u16x8*>(cs + rr * 136 + qd);
                dst[0] = s[0];
                dst[1] = s[1];
                dst[2] = s[2];
                dst[3] = s[3];
            }
        }
    }
}

// ================= fused edge attention + aggregation =================
__global__ __launch_bounds__(128)
void edge_fused(const unsigned short* __restrict__ kea,
                const unsigned short* __restrict__ qkv,
                const float* __restrict__ Waw, const float* __restrict__ baw,
                const int* __restrict__ rowptr, const int* __restrict__ src_s,
                unsigned short* __restrict__ agg)
{
    __shared__ float awsh[HH];
    __shared__ float WawS[HH * HH];
    __shared__ float bawS[HH];
    const int n = blockIdx.x;
    const int t = threadIdx.x;      // 0..127, 6 features each
    const int d0 = t * 6;
    const int h = t >> 4;           // 16 threads per head
    if (t < HH * HH) WawS[t] = Waw[t];
    if (t < HH) bawS[t] = baw[t];
    const int jlo = rowptr[n], jhi = rowptr[n + 1];
    const unsigned int* qr = reinterpret_cast<const unsigned int*>(qkv + (size_t)n * (3 * DD) + d0);
    float q[6];
    b2f2(qr[0], q[0], q[1]); b2f2(qr[1], q[2], q[3]); b2f2(qr[2], q[4], q[5]);
    float acc[6] = {0.f, 0.f, 0.f, 0.f, 0.f, 0.f};
    float sa = 0.f;
    constexpr float rs = 0.03608439182435161f; // 1/sqrt(768)
    __syncthreads();
    for (int j = jlo; j < jhi; j++) {
        int s = src_s[j];
        const unsigned int* ke = reinterpret_cast<const unsigned int*>(kea + (size_t)j * DD + d0);
        const unsigned int* kr = reinterpret_cast<const unsigned int*>(qkv + (size_t)s * (3 * DD) + DD + d0);
        const unsigned int* vr = reinterpret_cast<const unsigned int*>(qkv + (size_t)s * (3 * DD) + 2 * DD + d0);
        float part = 0.f;
        float ka, kb2, va, vb;
#pragma unroll
        for (int c = 0; c < 3; c++) {
            b2f2(ke[c], ka, kb2);
            b2f2(kr[c], va, vb);
            part = fmaf(q[2 * c], ka + va, part);
            part = fmaf(q[2 * c + 1], kb2 + vb, part);
        }
        part += __shfl_xor(part, 1);
        part += __shfl_xor(part, 2);
        part += __shfl_xor(part, 4);
        part += __shfl_xor(part, 8);
        if ((t & 15) == 0) awsh[h] = part;
        __syncthreads();
        float zz = bawS[h];
#pragma unroll
        for (int h2 = 0; h2 < HH; h2++) {
            float aw = awsh[h2] * rs;
            float tt = aw > 0.f ? aw : 0.2f * aw;
            zz = fmaf(tt, WawS[h2 * HH + h], zz);
        }
        float a = expf(zz);
        sa += a;
        float v0, v1;
#pragma unroll
        for (int c = 0; c < 3; c++) {
            b2f2(vr[c], v0, v1);
            acc[2 * c]     = fmaf(a, v0, acc[2 * c]);
            acc[2 * c + 1] = fmaf(a, v1, acc[2 * c + 1]);
        }
        __syncthreads();
    }
    float inv = (sa == 0.f) ? 1.f : 1.f / sa;
    unsigned int* ag = reinterpret_cast<unsigned int*>(agg + (size_t)n * DD + d0);
    ag[0] = packbf(acc[0] * inv, acc[1] * inv);
    ag[1] = packbf(acc[2] * inv, acc[3] * inv);
    ag[2] = packbf(acc[4] * inv, acc[5] * inv);
}

// one wave per node: z = lrelu(g)@Wla2 + bla2 ; la = softmax(z) ; out = x*la0 + h*la1
__global__ __launch_bounds__(256)
void combine_kernel(const unsigned short* __restrict__ g, const float* __restrict__ Wla2,
                    const float* __restrict__ bla2, unsigned short* __restrict__ x16,
                    const unsigned short* __restrict__ h, float* __restrict__ outf, int Nn)
{
    int w = threadIdx.x >> 6;
    int lane = threadIdx.x & 63;
    int n = blockIdx.x * 4 + w;
    if (n >= Nn) return;
    float z0 = 0.f, z1 = 0.f;
#pragma unroll
    for (int p = 0; p < 3; p++) {
        int d = p * 256 + lane * 4;
        const unsigned short* gp = g + (size_t)n * DD + d;
#pragma unroll
        for (int j = 0; j < 4; j++) {
            float gv = b2f(gp[j]);
            float tt = gv > 0.f ? gv : 0.2f * gv;
            z0 = fmaf(tt, Wla2[(d + j) * 2 + 0], z0);
            z1 = fmaf(tt, Wla2[(d + j) * 2 + 1], z1);
        }
    }
#pragma unroll
    for (int off = 32; off > 0; off >>= 1) {
        z0 += __shfl_xor(z0, off);
        z1 += __shfl_xor(z1, off);
    }
    z0 += bla2[0]; z1 += bla2[1];
    float mx = fmaxf(z0, z1);
    float e0v = expf(z0 - mx), e1v = expf(z1 - mx);
    float inv = 1.f / (e0v + e1v);
    float la0 = e0v * inv, la1 = e1v * inv;
#pragma unroll
    for (int p = 0; p < 3; p++) {
        int d = p * 256 + lane * 4;
        unsigned short* xp = x16 + (size_t)n * DD + d;
        const unsigned short* hp = h + (size_t)n * DD + d;
        float o[4];
#pragma unroll
        for (int j = 0; j < 4; j++)
            o[j] = b2f(xp[j]) * la0 + b2f(hp[j]) * la1;
#pragma unroll
        for (int j = 0; j < 4; j++) xp[j] = f2b_rne(o[j]);
        if (outf) {
            float4 ov = make_float4(o[0], o[1], o[2], o[3]);
            *reinterpret_cast<float4*>((float*)outf + (size_t)n * DD + d) = ov;
        }
    }
}

extern "C" void kernel_launch(void* const* d_in, const int* in_sizes, int n_in,
                              void* d_out, int out_size, void* d_ws, size_t ws_size,
                              hipStream_t stream)
{
    const int N = NN, E = EE;
    const float* x_in      = (const float*)d_in[0];
    const float* edge_attr = (const float*)d_in[1];
    const float* Wck = (const float*)d_in[2];
    const float* bck = (const float*)d_in[3];
    const float* Wq  = (const float*)d_in[4];
    const float* bq  = (const float*)d_in[5];
    const float* Wv  = (const float*)d_in[6];
    const float* bv  = (const float*)d_in[7];
    const float* Waw = (const float*)d_in[8];
    const float* baw = (const float*)d_in[9];
    const float* Wc  = (const float*)d_in[10];
    const float* bc  = (const float*)d_in[11];
    const float* Wlx = (const float*)d_in[12];
    const float* blx = (const float*)d_in[13];
    const float* Wla1 = (const float*)d_in[14];
    const float* bla1 = (const float*)d_in[15];
    const float* Wla2 = (const float*)d_in[16];
    const float* bla2 = (const float*)d_in[17];
    const int* eidx = (const int*)d_in[18];
    const int* srcp = eidx;       // edge_index[0]
    const int* dstp = eidx + E;   // edge_index[1]

    const size_t DDDD = (size_t)DD * DD;
    float* p = (float*)d_ws;
    const size_t NB = (size_t)N * DD;
    float* degf  = p; p += N;
    float* wfx32 = p; p += NL * DDDD;
    float* bfbuf = p; p += NL * DD;
    float* bqkvb = p; p += NL * 3 * DD;
    // int region
    int* rowptr = (int*)p;
    int* cursor = rowptr + (N + 1);
    int* perm   = cursor + N;
    int* src_s  = perm + E;
    p += (size_t)(2 * N + 1 + 2 * E + 63) / 64 * 64;
    // bf16 regions (counted in floats = elems/2)
    unsigned short* xb16  = (unsigned short*)p; p += NB / 2;
    unsigned short* hb16  = (unsigned short*)p; p += NB / 2;
    unsigned short* agg16 = (unsigned short*)p; p += NB / 2;
    unsigned short* qkv16 = (unsigned short*)p; p += 3 * NB / 2;   // [N][2304]
    unsigned short* ea16  = (unsigned short*)p; p += (size_t)E * DD / 2;
    unsigned short* kea16 = (unsigned short*)p; p += (size_t)E * DD / 2;
    unsigned short* gb16  = qkv16;                 // reuse after edge_fused
    // weights (all NL layers)
    unsigned short* wqkvt  = (unsigned short*)p; p += NL * 3 * DDDD / 2; // [l][2304][768]
    unsigned short* wcktopt= (unsigned short*)p; p += NL * DDDD / 2;
    unsigned short* wct    = (unsigned short*)p; p += NL * DDDD / 2;
    unsigned short* wla1tt = (unsigned short*)p; p += NL * DDDD / 2;
    unsigned short* wst3   = (unsigned short*)p; p += NL * 2 * DDDD / 2; // [l][768][1536]
    unsigned short* wlx16  = (unsigned short*)p; p += NL * DDDD / 2;

    // ================= setup (once) =================
    hipMemsetAsync(cursor, 0, N * sizeof(int), stream);
    deg_kernel<<<(E + 255) / 256, 256, 0, stream>>>(dstp, cursor);
    scan_kernel<<<1, 256, 0, stream>>>(cursor, rowptr, cursor);
    fill_perm<<<(E + 255) / 256, 256, 0, stream>>>(srcp, dstp, cursor, perm, src_s);
    degf_kernel<<<(N + 255) / 256, 256, 0, stream>>>(rowptr, degf);
    f2b_gather<<<(E * 96 + 255) / 256, 256, 0, stream>>>(edge_attr, perm, ea16);
    f2b_kernel<<<(N * 96 + 255) / 256, 256, 0, stream>>>(x_in, xb16, N * 96);

    // ---- batched weight prep (z = layer) ----
    dim3 gt3(DD / 32, DD / 32, NL);
    transpose_w<<<gt3, 256, 0, stream>>>(Wq, wqkvt, DD, DD, 0, DDDD, 3 * DDDD);
    transpose_w<<<gt3, 256, 0, stream>>>(Wck + DDDD, wqkvt + DDDD, DD, DD, 0, 2 * DDDD, 3 * DDDD);
    transpose_w<<<gt3, 256, 0, stream>>>(Wv, wqkvt + 2 * DDDD, DD, DD, 0, DDDD, 3 * DDDD);
    transpose_w<<<gt3, 256, 0, stream>>>(Wck, wcktopt, DD, DD, 0, 2 * DDDD, DDDD);
    transpose_w<<<gt3, 256, 0, stream>>>(Wc, wct, DD, DD, 0, DDDD, DDDD);
    transpose_w<<<gt3, 256, 0, stream>>>(Wla1, wla1tt, DD, DD, 0, 2 * DDDD, DDDD);
    transpose_w<<<gt3, 256, 0, stream>>>(Wla1 + DDDD, wst3, DD, 2 * DD, DD, 2 * DDDD, 2 * DDDD);
    f2b_kernel<<<(NL * DD * 96 + 255) / 256, 256, 0, stream>>>(Wlx, wlx16, NL * DD * 96);
    // wfx[l] = Wlx[l] @ Wla1_top[l]  (batched z=NL)
    gemm_mfma<<<dim3(6, 3, NL), 512, 0, stream>>>(wlx16, nullptr, wla1tt, nullptr, nullptr,
                                                  wfx32, nullptr, DD, DD, DD,
                                                  DDDD, DDDD, DDDD);
    transpose_w<<<gt3, 256, 0, stream>>>(wfx32, wst3, DD, 2 * DD, 0, DDDD, 2 * DDDD);
    biasf_kernel<<<dim3(3, NL), 256, 0, stream>>>(blx, Wla1, bla1, bfbuf);
    biasqkv_kernel<<<dim3(9, NL), 256, 0, stream>>>(bq, bv, bqkvb);

    // ================= layer loop =================
    for (int l = 0; l < NL; l++) {
        const float* bck_l = bck + (size_t)l * DD;
        const float* Waw_l = Waw + (size_t)l * HH * HH;
        const float* baw_l = baw + (size_t)l * HH;
        const float* bc_l  = bc  + (size_t)l * DD;
        const float* Wla2_l = Wla2 + (size_t)l * DD * 2;
        const float* bla2_l = bla2 + (size_t)l * 2;

        // ---- qkv node GEMM [N][2304] ----
        gemm_mfma<<<dim3(18, (N + 255) / 256), 512, 0, stream>>>(
            xb16, nullptr, wqkvt + (size_t)l * 3 * DDDD, bqkvb + (size_t)l * 3 * DD,
            nullptr, nullptr, qkv16, N, DD, 3 * DD, 0, 0, 0);
        // ---- kea edge GEMM [E][768] ----
        gemm_mfma<<<dim3(6, (E + 255) / 256), 512, 0, stream>>>(
            ea16, nullptr, wcktopt + (size_t)l * DDDD, bck_l,
            nullptr, nullptr, kea16, E, DD, DD, 0, 0, 0);
        // ---- fused attention + aggregation (single pass) ----
        edge_fused<<<N, 128, 0, stream>>>(kea16, qkv16, Waw_l, baw_l, rowptr, src_s, agg16);
        // ---- h = agg @ Wc + deg*bc (bf16 out) ----
        gemm_mfma<<<dim3(6, (N + 255) / 256), 512, 0, stream>>>(
            agg16, nullptr, wct + (size_t)l * DDDD, bc_l,
            degf, nullptr, hb16, N, DD, DD, 0, 0, 0);
        // ---- g = x@Wfx + h@Wla1_bot + bf ----
        gemm_mfma<<<dim3(6, (N + 255) / 256), 512, 0, stream>>>(
            xb16, hb16, wst3 + (size_t)l * 2 * DDDD, bfbuf + (size_t)l * DD,
            nullptr, nullptr, gb16, N, 2 * DD, DD, 0, 0, 0);
        // ---- gated combine ----
        combine_kernel<<<(N + 3) / 4, 256, 0, stream>>>(
            gb16, Wla2_l, bla2_l, xb16, hb16,
            (l == NL - 1) ? (float*)d_out : nullptr, N);
    }
}